// Round 9
// baseline (36.171 us; speedup 1.0000x reference)
//
#include <hip/hip_runtime.h>
#include <hip/hip_bf16.h>

// MADPSNet fused, round 9: r8's TLP (16 waves, 4/SIMD) x r6's held pipeline.
// Evidence chain: r6 (ring+fence, VGPR=128, 2w/SIMD) null -> depth insufficient
// at low TLP; r8 (no ring, 4w/SIMD) 40->~27us -> TLP works; r7 (over-budget)
// spilled. Compose: depth-2 B-prefetch ring (b[3][F]) + sched_barrier(0)
// between load block and MFMA cluster, single-buffered A, ~105 VGPR demand
// (hard cap 128 for a 1024-thread block). Compiler emits COUNTED waits for
// b[s%3] (2F newer loads stay in flight across the fence) = T4 mechanism.
// Everything else identical to r8.

typedef __attribute__((ext_vector_type(8))) short bf16x8;
typedef __attribute__((ext_vector_type(4))) float f32x4;

__device__ __forceinline__ ushort f2b(float x) {
    __hip_bfloat16 h = __float2bfloat16(x);
    return *reinterpret_cast<ushort*>(&h);
}

// swizzled LDS byte offset for bf16 (row, col); row stride = LD elems
__device__ __forceinline__ int swz_off(int row, int col, int LD) {
    const int chunk = col >> 3;
    const int phys  = chunk ^ (row & 7);
    return row * (LD * 2) + (phys << 4) + ((col & 7) << 1);
}

// ------------------------------------------------------------------ prep ---
// W[e][K][N] fp32 -> Wp[e][fg][s][lane][j] bf16 (MFMA fragment order):
//   n = fg*16 + (lane&15), k = s*32 + (lane>>4)*8 + j,  s = 0..K/32-1
__global__ __launch_bounds__(256)
void prep_weights(const float* __restrict__ Ws1, const float* __restrict__ Ws2,
                  const float* __restrict__ Wd1, const float* __restrict__ Wd2,
                  ushort* __restrict__ W1p, ushort* __restrict__ W2p,
                  ushort* __restrict__ W3p, ushort* __restrict__ W4p)
{
    const int layer = blockIdx.z;
    const int e  = blockIdx.y;
    const int fg = blockIdx.x;
    const float* W; ushort* Wp; int K, N;
    if (layer == 0)      { W = Ws1; Wp = W1p; K = 256; N = 512; }
    else if (layer == 1) { W = Ws2; Wp = W2p; K = 512; N = 256; }
    else if (layer == 2) { W = Wd1; Wp = W3p; K = 256; N = 512; }
    else                 { W = Wd2; Wp = W4p; K = 512; N = 128; }
    if (fg >= N / 16) return;
    const int NK = K / 32;
    W += (size_t)e * K * N;

    __shared__ float tile[512][17];
    const int tid = threadIdx.x;
    const int n0 = fg * 16;
    for (int idx = tid; idx < K * 16; idx += 256)
        tile[idx >> 4][idx & 15] = W[(size_t)(idx >> 4) * N + n0 + (idx & 15)];
    __syncthreads();
    ushort* dst = Wp + (((size_t)e * (N / 16) + fg) * NK) * 512;
    for (int w = tid; w < NK * 64; w += 256) {
        const int s    = w >> 6;
        const int lane = w & 63;
        const int c    = lane & 15;
        const int kb   = s * 32 + ((lane >> 4) << 3);
        bf16x8 v;
        #pragma unroll
        for (int j = 0; j < 8; ++j)
            v[j] = (short)f2b(tile[kb + j][c]);
        *reinterpret_cast<bf16x8*>(&dst[(size_t)w * 8]) = v;
    }
}

// ----------------------------------------------------------- fused layer ---
// A: LDS [64][K] bf16 swizzled. B: packed global (fragment order).
// 16 waves: MG row-groups x NG col-groups (MG*NG=16), F=N/16/NG frags/wave.
// B prefetched 2 steps ahead in a 3-slot ring; sched_barrier(0) pins the
// load block above the MFMA cluster so waits stay COUNTED (loads in flight).
template<int K, int N, int MG, int RELU>
__device__ __forceinline__ void layer_mlp(
    const ushort* __restrict__ Wp, const float* __restrict__ bias,
    const ushort* __restrict__ sIn, ushort* __restrict__ sOut,
    float* __restrict__ gOut, int wid, int lane)
{
    constexpr int NG = 16 / MG;          // col groups
    constexpr int F  = N / 16 / NG;      // frags per wave
    constexpr int M4 = 4 / MG;           // m-frags per wave
    constexpr int NK = K / 32;           // k-steps
    const int r15 = lane & 15, lh = lane >> 4;
    const int wc = wid % NG, wr = wid / NG;
    const int rowBase = wr * (64 / MG);

    const ushort* bBase = Wp + ((size_t)(wc * F) * NK) * 512 + (size_t)lane * 8;

    f32x4 acc[M4][F];
    #pragma unroll
    for (int m = 0; m < M4; ++m)
        #pragma unroll
        for (int f = 0; f < F; ++f)
            acc[m][f] = (f32x4){0.f, 0.f, 0.f, 0.f};

    bf16x8 b[3][F];
    auto loadB = [&](int buf, int s) {
        #pragma unroll
        for (int f = 0; f < F; ++f)
            b[buf][f] = *reinterpret_cast<const bf16x8*>(
                bBase + ((size_t)f * NK + s) * 512);
    };

    loadB(0, 0);
    loadB(1, 1);

    #pragma unroll
    for (int ss = 0; ss < NK; ++ss) {
        if (ss + 2 < NK) loadB((ss + 2) % 3, ss + 2);
        const int k0 = ss * 32;
        bf16x8 a[M4];
        #pragma unroll
        for (int m = 0; m < M4; ++m) {
            const int row  = rowBase + m * 16 + r15;
            const int phys = ((k0 >> 3) + lh) ^ (row & 7);
            a[m] = *reinterpret_cast<const bf16x8*>(
                reinterpret_cast<const char*>(sIn) + row * (K * 2) + (phys << 4));
        }
        // pin loads above, MFMAs below; MFMA(ss) then co-schedules with
        // loads(ss+3) in the next region -> issue stream stays interleaved.
        __builtin_amdgcn_sched_barrier(0);
        #pragma unroll
        for (int m = 0; m < M4; ++m)
            #pragma unroll
            for (int f = 0; f < F; ++f)
                acc[m][f] = __builtin_amdgcn_mfma_f32_16x16x32_bf16(
                    a[m], b[ss % 3][f], acc[m][f], 0, 0, 0);
    }

    // epilogue
    #pragma unroll
    for (int f = 0; f < F; ++f) {
        const int col = (wc * F + f) * 16 + r15;
        const float bv = bias[col];
        #pragma unroll
        for (int m = 0; m < M4; ++m) {
            #pragma unroll
            for (int j = 0; j < 4; ++j) {
                const int row = rowBase + m * 16 + lh * 4 + j;   // C/D (m89)
                float v = acc[m][f][j] + bv;
                if (RELU) v = fmaxf(v, 0.f);
                if (gOut) {
                    gOut[(size_t)row * N + col] = v;
                } else {
                    *reinterpret_cast<ushort*>(
                        reinterpret_cast<char*>(sOut) + swz_off(row, col, N)) = f2b(v);
                }
            }
        }
    }
}

// ----------------------------------------------------------- fused kernel ---
__global__ __launch_bounds__(1024, 4)
void madps_fused(const float* __restrict__ X,
                 const int* __restrict__ sel_s, const int* __restrict__ sel_d,
                 const ushort* __restrict__ W1p, const ushort* __restrict__ W2p,
                 const ushort* __restrict__ W3p, const ushort* __restrict__ W4p,
                 const float* __restrict__ bs1, const float* __restrict__ bs2,
                 const float* __restrict__ bd1, const float* __restrict__ bd2,
                 float* __restrict__ out)
{
    constexpr int S = 256, H1 = 512, H2 = 256, D1 = 512, D2 = 128;

    __shared__ __align__(16) ushort buf0[64 * 256];   // 32 KB: X, then sh
    __shared__ __align__(16) ushort buf1[64 * 512];   // 64 KB: h, then d

    const int bid   = blockIdx.x;
    const int agent = bid & 7;          // agent == XCD -> weights L2-resident
    const int rb    = bid >> 3;         // row-block within agent (0..31)
    const int tid   = threadIdx.x;
    const int lane  = tid & 63;
    const int wid   = tid >> 6;         // 0..15

    const long long es = sel_s[agent];
    const long long ed = sel_d[agent];

    const float* Xa = X + ((size_t)agent * 2048 + (size_t)rb * 64) * S;

    // ---- stage X [64][256] fp32 -> buf0 bf16 (swizzled) ----
    #pragma unroll
    for (int i = 0; i < 4; ++i) {
        const int flat4 = i * 1024 + tid;       // float4 index, 64/row
        const int row = flat4 >> 6;
        const int c4  = flat4 & 63;
        const float4 v = reinterpret_cast<const float4*>(Xa)[flat4];
        ushort4 o;
        o.x = f2b(v.x); o.y = f2b(v.y); o.z = f2b(v.z); o.w = f2b(v.w);
        const int byteoff = (((c4 >> 1) ^ (row & 7)) << 4) | ((c4 & 1) << 3);
        *reinterpret_cast<ushort4*>(
            reinterpret_cast<char*>(buf0) + row * 512 + byteoff) = o;
    }
    __syncthreads();

    // L1: X(buf0, K=256) @ W1p -> relu -> h(buf1, N=512)
    layer_mlp<S, H1, 1, 1>(W1p + (size_t)es * ((H1 / 16) * (S / 32) * 512),
                           bs1 + es * H1, buf0, buf1, nullptr, wid, lane);
    __syncthreads();
    // L2: h(buf1, K=512) @ W2p -> relu -> sh(buf0, N=256)
    layer_mlp<H1, H2, 1, 1>(W2p + (size_t)es * ((H2 / 16) * (H1 / 32) * 512),
                            bs2 + es * H2, buf1, buf0, nullptr, wid, lane);
    __syncthreads();
    // L3: sh(buf0, K=256) @ W3p -> relu -> d(buf1, N=512)
    layer_mlp<H2, D1, 1, 1>(W3p + (size_t)ed * ((D1 / 16) * (H2 / 32) * 512),
                            bd1 + ed * D1, buf0, buf1, nullptr, wid, lane);
    __syncthreads();
    // L4: d(buf1, K=512) @ W4p + bias -> out fp32 [64][128]  (2x8 M-split)
    float* outP = out + ((size_t)agent * 2048 + (size_t)rb * 64) * D2;
    layer_mlp<D1, D2, 2, 0>(W4p + (size_t)ed * ((D2 / 16) * (D1 / 32) * 512),
                            bd2 + ed * D2, buf1, nullptr, outP, wid, lane);
}

// --------------------------------------------------------------- launch ---
extern "C" void kernel_launch(void* const* d_in, const int* in_sizes, int n_in,
                              void* d_out, int out_size, void* d_ws, size_t ws_size,
                              hipStream_t stream)
{
    constexpr int E = 8, S = 256, H1 = 512, H2 = 256, D1 = 512, D2 = 128;

    const float* inputs = (const float*)d_in[0];
    const int*   sel_s  = (const int*)d_in[1];
    const int*   sel_d  = (const int*)d_in[2];
    const float* Ws1 = (const float*)d_in[3];
    const float* bs1 = (const float*)d_in[4];
    const float* Ws2 = (const float*)d_in[5];
    const float* bs2 = (const float*)d_in[6];
    const float* Wd1 = (const float*)d_in[7];
    const float* bd1 = (const float*)d_in[8];
    const float* Wd2 = (const float*)d_in[9];
    const float* bd2 = (const float*)d_in[10];
    float* out = (float*)d_out;

    // workspace: packed bf16 weights
    ushort* W1p = (ushort*)d_ws;
    ushort* W2p = W1p + (size_t)E * S * H1;
    ushort* W3p = W2p + (size_t)E * H1 * H2;
    ushort* W4p = W3p + (size_t)E * H2 * D1;

    prep_weights<<<dim3(32, E, 4), 256, 0, stream>>>(
        Ws1, Ws2, Wd1, Wd2, W1p, W2p, W3p, W4p);

    madps_fused<<<dim3(256), dim3(1024), 0, stream>>>(
        inputs, sel_s, sel_d, W1p, W2p, W3p, W4p,
        bs1, bs2, bd1, bd2, out);
}

// Round 10
// 34.146 us; speedup vs baseline: 1.0593x; 1.0593x over previous
//
#include <hip/hip_runtime.h>
#include <hip/hip_bf16.h>

// MADPSNet fused, round 10: r8 base (best: 34.8us) + swapped-operand MFMA
// epilogue. Evidence: r6/r9 scheduling interventions null (3rd confirmation
// of m131-m141); r8's 16-wave TLP is the win. Remaining overhead candidates:
// scalar ds_write_b16 epilogue (32 scalar writes/wave/layer, C/D j-values
// span 4 rows -> unvectorizable). Fix: mfma(b, a, acc) transposes C/D
// (m89 mapping is operand-symmetric): lane holds row=lane&15 and 4
// CONSECUTIVE cols -> one ds_write_b64 per (m,f), 4x fewer LDS writes,
// float4 bias loads, float4 final stores.
// Everything else identical to r8 (16 waves, packed-B from L2, no ring).

typedef __attribute__((ext_vector_type(8))) short bf16x8;
typedef __attribute__((ext_vector_type(4))) float f32x4;

__device__ __forceinline__ ushort f2b(float x) {
    __hip_bfloat16 h = __float2bfloat16(x);
    return *reinterpret_cast<ushort*>(&h);
}

// ------------------------------------------------------------------ prep ---
// W[e][K][N] fp32 -> Wp[e][fg][s][lane][j] bf16 (MFMA fragment order):
//   n = fg*16 + (lane&15), k = s*32 + (lane>>4)*8 + j,  s = 0..K/32-1
__global__ __launch_bounds__(256)
void prep_weights(const float* __restrict__ Ws1, const float* __restrict__ Ws2,
                  const float* __restrict__ Wd1, const float* __restrict__ Wd2,
                  ushort* __restrict__ W1p, ushort* __restrict__ W2p,
                  ushort* __restrict__ W3p, ushort* __restrict__ W4p)
{
    const int layer = blockIdx.z;
    const int e  = blockIdx.y;
    const int fg = blockIdx.x;
    const float* W; ushort* Wp; int K, N;
    if (layer == 0)      { W = Ws1; Wp = W1p; K = 256; N = 512; }
    else if (layer == 1) { W = Ws2; Wp = W2p; K = 512; N = 256; }
    else if (layer == 2) { W = Wd1; Wp = W3p; K = 256; N = 512; }
    else                 { W = Wd2; Wp = W4p; K = 512; N = 128; }
    if (fg >= N / 16) return;
    const int NK = K / 32;
    W += (size_t)e * K * N;

    __shared__ float tile[512][17];
    const int tid = threadIdx.x;
    const int n0 = fg * 16;
    for (int idx = tid; idx < K * 16; idx += 256)
        tile[idx >> 4][idx & 15] = W[(size_t)(idx >> 4) * N + n0 + (idx & 15)];
    __syncthreads();
    ushort* dst = Wp + (((size_t)e * (N / 16) + fg) * NK) * 512;
    for (int w = tid; w < NK * 64; w += 256) {
        const int s    = w >> 6;
        const int lane = w & 63;
        const int c    = lane & 15;
        const int kb   = s * 32 + ((lane >> 4) << 3);
        bf16x8 v;
        #pragma unroll
        for (int j = 0; j < 8; ++j)
            v[j] = (short)f2b(tile[kb + j][c]);
        *reinterpret_cast<bf16x8*>(&dst[(size_t)w * 8]) = v;
    }
}

// ----------------------------------------------------------- fused layer ---
// A: LDS [64][K] bf16 swizzled. B: packed global (fragment order).
// 16 waves: MG row-groups x NG col-groups (MG*NG=16), F=N/16/NG frags/wave.
// mfma(b, a, acc): D transposed -> lane = (row r15, 4 consecutive cols
// lh*4+j) -> vector epilogue (ds_write_b64 / float4 stores).
template<int K, int N, int MG, int RELU>
__device__ __forceinline__ void layer_mlp(
    const ushort* __restrict__ Wp, const float* __restrict__ bias,
    const ushort* __restrict__ sIn, ushort* __restrict__ sOut,
    float* __restrict__ gOut, int wid, int lane)
{
    constexpr int NG = 16 / MG;          // col groups
    constexpr int F  = N / 16 / NG;      // frags per wave
    constexpr int M4 = 4 / MG;           // m-frags per wave
    constexpr int NK = K / 32;           // k-steps
    const int r15 = lane & 15, lh = lane >> 4;
    const int wc = wid % NG, wr = wid / NG;
    const int rowBase = wr * (64 / MG);

    const ushort* bBase = Wp + ((size_t)(wc * F) * NK) * 512 + (size_t)lane * 8;

    f32x4 acc[M4][F];
    #pragma unroll
    for (int m = 0; m < M4; ++m)
        #pragma unroll
        for (int f = 0; f < F; ++f)
            acc[m][f] = (f32x4){0.f, 0.f, 0.f, 0.f};

    #pragma unroll
    for (int s = 0; s < NK; ++s) {
        const int k0 = s * 32;
        bf16x8 a[M4];
        #pragma unroll
        for (int m = 0; m < M4; ++m) {
            const int row  = rowBase + m * 16 + r15;
            const int phys = ((k0 >> 3) + lh) ^ (row & 7);
            a[m] = *reinterpret_cast<const bf16x8*>(
                reinterpret_cast<const char*>(sIn) + row * (K * 2) + (phys << 4));
        }
        bf16x8 b[F];
        #pragma unroll
        for (int f = 0; f < F; ++f)
            b[f] = *reinterpret_cast<const bf16x8*>(
                bBase + ((size_t)f * NK + s) * 512);
        // swapped operands: D[n][row] -> lane&15 = row, (lh*4+j) = col
        #pragma unroll
        for (int m = 0; m < M4; ++m)
            #pragma unroll
            for (int f = 0; f < F; ++f)
                acc[m][f] = __builtin_amdgcn_mfma_f32_16x16x32_bf16(
                    b[f], a[m], acc[m][f], 0, 0, 0);
    }

    // epilogue: lane holds (row = rowBase+m*16+r15, cols cbase..cbase+3)
    #pragma unroll
    for (int f = 0; f < F; ++f) {
        const int cbase = (wc * F + f) * 16 + lh * 4;
        const float4 bv = *reinterpret_cast<const float4*>(&bias[cbase]);
        #pragma unroll
        for (int m = 0; m < M4; ++m) {
            const int row = rowBase + m * 16 + r15;
            float v0 = acc[m][f][0] + bv.x;
            float v1 = acc[m][f][1] + bv.y;
            float v2 = acc[m][f][2] + bv.z;
            float v3 = acc[m][f][3] + bv.w;
            if (RELU) {
                v0 = fmaxf(v0, 0.f); v1 = fmaxf(v1, 0.f);
                v2 = fmaxf(v2, 0.f); v3 = fmaxf(v3, 0.f);
            }
            if (gOut) {
                *reinterpret_cast<float4*>(&gOut[(size_t)row * N + cbase]) =
                    (float4){v0, v1, v2, v3};
            } else {
                const uint lo = ((uint)f2b(v1) << 16) | (uint)f2b(v0);
                const uint hi = ((uint)f2b(v3) << 16) | (uint)f2b(v2);
                const int byteoff = row * (N * 2) +
                    ((((cbase >> 3) ^ (row & 7))) << 4) + ((cbase & 7) << 1);
                *reinterpret_cast<uint2*>(
                    reinterpret_cast<char*>(sOut) + byteoff) = (uint2){lo, hi};
            }
        }
    }
}

// ----------------------------------------------------------- fused kernel ---
__global__ __launch_bounds__(1024, 4)
void madps_fused(const float* __restrict__ X,
                 const int* __restrict__ sel_s, const int* __restrict__ sel_d,
                 const ushort* __restrict__ W1p, const ushort* __restrict__ W2p,
                 const ushort* __restrict__ W3p, const ushort* __restrict__ W4p,
                 const float* __restrict__ bs1, const float* __restrict__ bs2,
                 const float* __restrict__ bd1, const float* __restrict__ bd2,
                 float* __restrict__ out)
{
    constexpr int S = 256, H1 = 512, H2 = 256, D1 = 512, D2 = 128;

    __shared__ __align__(16) ushort buf0[64 * 256];   // 32 KB: X, then sh
    __shared__ __align__(16) ushort buf1[64 * 512];   // 64 KB: h, then d

    const int bid   = blockIdx.x;
    const int agent = bid & 7;          // agent == XCD -> weights L2-resident
    const int rb    = bid >> 3;         // row-block within agent (0..31)
    const int tid   = threadIdx.x;
    const int lane  = tid & 63;
    const int wid   = tid >> 6;         // 0..15

    const long long es = sel_s[agent];
    const long long ed = sel_d[agent];

    const float* Xa = X + ((size_t)agent * 2048 + (size_t)rb * 64) * S;

    // ---- stage X [64][256] fp32 -> buf0 bf16 (swizzled) ----
    #pragma unroll
    for (int i = 0; i < 4; ++i) {
        const int flat4 = i * 1024 + tid;       // float4 index, 64/row
        const int row = flat4 >> 6;
        const int c4  = flat4 & 63;
        const float4 v = reinterpret_cast<const float4*>(Xa)[flat4];
        ushort4 o;
        o.x = f2b(v.x); o.y = f2b(v.y); o.z = f2b(v.z); o.w = f2b(v.w);
        const int byteoff = (((c4 >> 1) ^ (row & 7)) << 4) | ((c4 & 1) << 3);
        *reinterpret_cast<ushort4*>(
            reinterpret_cast<char*>(buf0) + row * 512 + byteoff) = o;
    }
    __syncthreads();

    // L1: X(buf0, K=256) @ W1p -> relu -> h(buf1, N=512)
    layer_mlp<S, H1, 1, 1>(W1p + (size_t)es * ((H1 / 16) * (S / 32) * 512),
                           bs1 + es * H1, buf0, buf1, nullptr, wid, lane);
    __syncthreads();
    // L2: h(buf1, K=512) @ W2p -> relu -> sh(buf0, N=256)
    layer_mlp<H1, H2, 1, 1>(W2p + (size_t)es * ((H2 / 16) * (H1 / 32) * 512),
                            bs2 + es * H2, buf1, buf0, nullptr, wid, lane);
    __syncthreads();
    // L3: sh(buf0, K=256) @ W3p -> relu -> d(buf1, N=512)
    layer_mlp<H2, D1, 1, 1>(W3p + (size_t)ed * ((D1 / 16) * (H2 / 32) * 512),
                            bd1 + ed * D1, buf0, buf1, nullptr, wid, lane);
    __syncthreads();
    // L4: d(buf1, K=512) @ W4p + bias -> out fp32 [64][128]  (2x8 M-split)
    float* outP = out + ((size_t)agent * 2048 + (size_t)rb * 64) * D2;
    layer_mlp<D1, D2, 2, 0>(W4p + (size_t)ed * ((D2 / 16) * (D1 / 32) * 512),
                            bd2 + ed * D2, buf1, nullptr, outP, wid, lane);
}

// --------------------------------------------------------------- launch ---
extern "C" void kernel_launch(void* const* d_in, const int* in_sizes, int n_in,
                              void* d_out, int out_size, void* d_ws, size_t ws_size,
                              hipStream_t stream)
{
    constexpr int E = 8, S = 256, H1 = 512, H2 = 256, D1 = 512, D2 = 128;

    const float* inputs = (const float*)d_in[0];
    const int*   sel_s  = (const int*)d_in[1];
    const int*   sel_d  = (const int*)d_in[2];
    const float* Ws1 = (const float*)d_in[3];
    const float* bs1 = (const float*)d_in[4];
    const float* Ws2 = (const float*)d_in[5];
    const float* bs2 = (const float*)d_in[6];
    const float* Wd1 = (const float*)d_in[7];
    const float* bd1 = (const float*)d_in[8];
    const float* Wd2 = (const float*)d_in[9];
    const float* bd2 = (const float*)d_in[10];
    float* out = (float*)d_out;

    // workspace: packed bf16 weights
    ushort* W1p = (ushort*)d_ws;
    ushort* W2p = W1p + (size_t)E * S * H1;
    ushort* W3p = W2p + (size_t)E * H1 * H2;
    ushort* W4p = W3p + (size_t)E * H2 * D1;

    prep_weights<<<dim3(32, E, 4), 256, 0, stream>>>(
        Ws1, Ws2, Wd1, Wd2, W1p, W2p, W3p, W4p);

    madps_fused<<<dim3(256), dim3(1024), 0, stream>>>(
        inputs, sel_s, sel_d, W1p, W2p, W3p, W4p,
        bs1, bs2, bd1, bd2, out);
}